// Round 8
// baseline (78.536 us; speedup 1.0000x reference)
//
#include <hip/hip_runtime.h>
#include <math.h>

#define B 32
#define S 512
#define E 512
#define FEAT 256
#define ATT 10
#define NCLS 8

using short8 = __attribute__((ext_vector_type(8))) short;
using f32x4  = __attribute__((ext_vector_type(4))) float;

// RNE float->bf16 (finite inputs)
__device__ __forceinline__ unsigned short f2bf(float f) {
    unsigned int u = __float_as_uint(f);
    return (unsigned short)((u + 0x7fffu + ((u >> 16) & 1u)) >> 16);
}

// async global->LDS, 16B/lane; LDS dest is wave-uniform base + lane*16 (HW)
__device__ __forceinline__ void gl16(const void* g, void* l) {
    __builtin_amdgcn_global_load_lds(
        (const __attribute__((address_space(1))) unsigned int*)g,
        (__attribute__((address_space(3))) unsigned int*)l, 16, 0, 0);
}

// ---------------------------------------------------------------------------
// Fused front: blocks [0,2048): embed gather + bf16 ex + scores/attn (padded
// to 12 floats/row). Blocks [2048,2304): Wh -> Whk16 transpose + ex tail pad.
// Block 2304: init d_out to bfc (k_chc atomicAdds partials; replay-safe).
__global__ __launch_bounds__(256) void k_front(
        const int* __restrict__ x, const float* __restrict__ emb,
        const float* __restrict__ A, const float* __restrict__ Wh,
        const float* __restrict__ bfc, unsigned short* __restrict__ ex16,
        unsigned short* __restrict__ Whk16,
        float* __restrict__ sc12, float* __restrict__ at12,
        float* __restrict__ out) {
    const int blk = blockIdx.x;
    const int tid = threadIdx.x;
    if (blk < 2048) {
        const int wave = tid >> 6, lane = tid & 63;
        // per-lane A slice (rows lane*8..lane*8+7 = 80 contiguous floats)
        f32x4 av4[20];
        const f32x4* ap4 = (const f32x4*)(A + (size_t)lane * 80);
#pragma unroll
        for (int q = 0; q < 20; ++q) av4[q] = ap4[q];
#pragma unroll
        for (int rep = 0; rep < 2; ++rep) {
            const int bs = blk * 8 + wave * 2 + rep;
            const int row = x[bs];
            const f32x4* src = (const f32x4*)(emb + (size_t)row * E);
            const f32x4 v0 = src[lane * 2], v1 = src[lane * 2 + 1];
            float v[8] = {v0[0], v0[1], v0[2], v0[3], v1[0], v1[1], v1[2], v1[3]};

            short8 sv;
#pragma unroll
            for (int j = 0; j < 8; ++j) sv[j] = (short)f2bf(v[j]);
            *(short8*)(ex16 + (size_t)bs * E + lane * 8) = sv;

            float acc[ATT] = {};
#pragma unroll
            for (int j = 0; j < 8; ++j)
#pragma unroll
                for (int a = 0; a < ATT; ++a) {
                    const int idx = j * ATT + a;
                    acc[a] = fmaf(v[j], av4[idx >> 2][idx & 3], acc[a]);
                }
#pragma unroll
            for (int a = 0; a < ATT; ++a)
#pragma unroll
                for (int off = 1; off < 64; off <<= 1) acc[a] += __shfl_xor(acc[a], off);

            if (lane == 0) {
                float m = -1e30f;
#pragma unroll
                for (int a = 0; a < ATT; ++a) m = fmaxf(m, acc[a]);
                float ev[ATT], sum = 0.f;
#pragma unroll
                for (int a = 0; a < ATT; ++a) { ev[a] = expf(acc[a] - m); sum += ev[a]; }
                const float inv = 1.f / sum;
                float* sp = sc12 + (size_t)bs * 12;
                float* tp = at12 + (size_t)bs * 12;
                *(f32x4*)(sp)     = (f32x4){acc[0], acc[1], acc[2], acc[3]};
                *(f32x4*)(sp + 4) = (f32x4){acc[4], acc[5], acc[6], acc[7]};
                *(f32x4*)(sp + 8) = (f32x4){acc[8], acc[9], 0.f, 0.f};
                *(f32x4*)(tp)     = (f32x4){ev[0] * inv, ev[1] * inv, ev[2] * inv, ev[3] * inv};
                *(f32x4*)(tp + 4) = (f32x4){ev[4] * inv, ev[5] * inv, ev[6] * inv, ev[7] * inv};
                *(f32x4*)(tp + 8) = (f32x4){ev[8] * inv, ev[9] * inv, 0.f, 0.f};
            }
        }
    } else if (blk < 2048 + FEAT) {
        const int f = blk - 2048;
        const float* src = Wh + (size_t)f * (E * 3);
        unsigned short* dst = Whk16 + (size_t)f * (E * 3);
#pragma unroll
        for (int i = 0; i < 6; ++i) {
            const int kk = tid + i * 256;
            dst[kk] = f2bf(src[(kk & 511) * 3 + (kk >> 9)]);
        }
        if (f == 0) {
            for (int i = tid; i < 2 * E; i += 256) ex16[(size_t)B * S * E + i] = 0;
        }
    } else {
        // init out[b][n] = bfc[n] (k_chc accumulates on top)
        if (tid < B * NCLS) out[tid] = bfc[tid & 7];
    }
}

// ---------------------------------------------------------------------------
// bf16 MFMA implicit-im2col conv GEMM, 2-way K-split, A DIRECT FROM L2.
// 8 waves: group g = wave>>2 handles K-half [g*768,+768) in 12 BK=64 steps;
// within group 2x2 waves, 64x64 wave tiles (4x4 frags of 16x16x32).
// B (ex) staged in LDS via global_load_lds + XOR slot swizzle (2 bufs x
// 2 groups x 16KB = 64KB). A (Whk, 768KB, shared by 64 blocks -> L2-hot)
// loaded direct global->VGPR, register-double-buffered (avA/avB, static
// indexing), issued with stage(t+1) BEFORE compute(t) so the ~2000cyc
// compute covers L2 latency. vmcnt(0)+barrier once per step.
// Cross-group K reduction through LDS (64KB, exact reuse), then max-epilogue
// (valid l < S-2) -> Cpart[b][f][z*2+wn] (8 partials).
__global__ __launch_bounds__(512) void k_conv(const unsigned short* __restrict__ Whk,
                                              const unsigned short* __restrict__ ex16,
                                              float* __restrict__ Cpart) {
    __shared__ __align__(16) unsigned short lds[2][16384];  // 2 bufs x 32KB (B only)
    const int b = blockIdx.x;
    const int fbase = blockIdx.y * 128;
    const int lbase = blockIdx.z * 128;
    const int tid = threadIdx.x;
    const int wave = tid >> 6, lane = tid & 63;
    const int g = wave >> 2;                  // K-half group
    const int sub = wave & 3;                 // wave within group
    const int wm = sub >> 1, wn = sub & 1;    // 2x2 wave grid
    const int lane15 = lane & 15, g4 = lane >> 4;
    const int tg = sub * 64 + lane;           // 0..255 within group
    const int rr = tg >> 3, slot = tg & 7;    // staging row / 16B slot
    const unsigned short* exb = ex16 + (size_t)b * S * E;
    // per-lane A base: row = fbase + wm*64 + lane15, k-offset g*768 + g4*8
    const unsigned short* WA =
        Whk + (size_t)(fbase + wm * 64 + lane15) * 1536 + g * 768 + g4 * 8;

    f32x4 acc[4][4];
#pragma unroll
    for (int mf = 0; mf < 4; ++mf)
#pragma unroll
        for (int nf = 0; nf < 4; ++nf) acc[mf][nf] = (f32x4){0.f, 0.f, 0.f, 0.f};

    // stage this group's B K-tile t: B[128 rows][64 k], 4 gl16/wave
    auto stage = [&](int t, unsigned short* buf) {
        const int kkg = g * 768 + (t << 6);   // global k offset
        const int tap = kkg >> 9;             // conv tap 0..2
        const int e0  = kkg & 511;            // e-offset within tap
        unsigned short* lb = buf + g * 8192;
#pragma unroll
        for (int i = 0; i < 4; ++i) {
            const int r = i * 32 + rr;
            gl16(exb + (size_t)(lbase + r + tap) * E + e0 + ((slot ^ (r & 7)) << 3),
                 lb + i * 2048 + sub * 512);
        }
    };

    // A fragments for K-tile t, direct from global (raw layout, no swizzle)
    auto loadA = [&](int t, short8 (&av)[2][4]) {
#pragma unroll
        for (int kh = 0; kh < 2; ++kh)
#pragma unroll
            for (int mf = 0; mf < 4; ++mf)
                av[kh][mf] = *(const short8*)(WA + mf * 16 * 1536 + (t << 6) + kh * 32);
    };

    auto compute = [&](const unsigned short* buf, const short8 (&av)[2][4]) {
        const char* lb = (const char*)(buf + g * 8192);
#pragma unroll
        for (int kh = 0; kh < 2; ++kh) {
            short8 bv[4];
#pragma unroll
            for (int nf = 0; nf < 4; ++nf) {
                const int row = wn * 64 + nf * 16 + lane15;
                bv[nf] = *(const short8*)(lb + row * 128 +
                                          ((((kh << 2) | g4) ^ (row & 7)) << 4));
            }
#pragma unroll
            for (int mf = 0; mf < 4; ++mf)
#pragma unroll
                for (int nf = 0; nf < 4; ++nf)
                    acc[mf][nf] = __builtin_amdgcn_mfma_f32_16x16x32_bf16(
                        av[kh][mf], bv[nf], acc[mf][nf], 0, 0, 0);
        }
    };

    short8 avA[2][4], avB[2][4];
    stage(0, lds[0]);
    loadA(0, avA);
    asm volatile("s_waitcnt vmcnt(0)" ::: "memory");
    __builtin_amdgcn_s_barrier();

    for (int t = 0; t < 12; t += 2) {
        // even step: compute lds[0]/avA; prefetch t+1 -> lds[1]/avB
        stage(t + 1, lds[1]);
        loadA(t + 1, avB);
        compute(lds[0], avA);
        asm volatile("s_waitcnt vmcnt(0)" ::: "memory");
        __builtin_amdgcn_s_barrier();
        // odd step: compute lds[1]/avB; prefetch t+2 -> lds[0]/avA
        if (t + 2 < 12) { stage(t + 2, lds[0]); loadA(t + 2, avA); }
        compute(lds[1], avB);
        if (t + 2 < 12) {
            asm volatile("s_waitcnt vmcnt(0)" ::: "memory");
            __builtin_amdgcn_s_barrier();
        }
    }

    // cross-group K reduction: group1 -> LDS (frag-major: lane-contiguous,
    // conflict-free), group0 adds. 16 frags x 256 lanes x 16B = 64KB = lds.
    __syncthreads();
    f32x4* lf = (f32x4*)&lds[0][0];
    if (g == 1) {
#pragma unroll
        for (int mf = 0; mf < 4; ++mf)
#pragma unroll
            for (int nf = 0; nf < 4; ++nf)
                lf[(mf * 4 + nf) * 256 + sub * 64 + lane] = acc[mf][nf];
    }
    __syncthreads();
    if (g == 0) {
#pragma unroll
        for (int mf = 0; mf < 4; ++mf)
#pragma unroll
            for (int nf = 0; nf < 4; ++nf)
                acc[mf][nf] += lf[(mf * 4 + nf) * 256 + sub * 64 + lane];

        // epilogue: C/D layout col(l)=lane&15, row(f)=(lane>>4)*4+j (m89/m91)
#pragma unroll
        for (int mf = 0; mf < 4; ++mf) {
#pragma unroll
            for (int j = 0; j < 4; ++j) {
                float m = -1e30f;
#pragma unroll
                for (int nf = 0; nf < 4; ++nf) {
                    const int l = lbase + wn * 64 + nf * 16 + lane15;
                    if (l < S - 2) m = fmaxf(m, acc[mf][nf][j]);
                }
#pragma unroll
                for (int off = 1; off < 16; off <<= 1) m = fmaxf(m, __shfl_xor(m, off));
                if (lane15 == 0) {
                    const int f = fbase + wm * 64 + mf * 16 + g4 * 4 + j;
                    Cpart[(((size_t)b * FEAT + f) << 3) + blockIdx.z * 2 + wn] = m;
                }
            }
        }
    }
}

// ---------------------------------------------------------------------------
// c-branch + combine + fused FC: each wave owns 8 f's.
// g[f][a] = sum_t Wc[f,t]*scores[b,t,a]; mc[f] = max_l attn[b,l,:].g[f];
// hc = tanh(max_h + mc + tb[f]); then block-local dot with Wfc and one
// atomicAdd per (b,n) into out (pre-initialized to bfc by k_front).
__global__ __launch_bounds__(256) void k_chc(
        const float* __restrict__ sc12, const float* __restrict__ at12,
        const float* __restrict__ Wc, const float* __restrict__ Cpart,
        const float* __restrict__ tb, const float* __restrict__ Wfc,
        float* __restrict__ out) {
    const int fg = blockIdx.x, b = blockIdx.y;
    const int tid = threadIdx.x;
    const int wave = tid >> 6, lane = tid & 63;
    const int f0 = fg * 32 + wave * 8;
    __shared__ float shc[32];
    __shared__ float ps[256];

    f32x4 wc[8][2];
#pragma unroll
    for (int ff = 0; ff < 8; ++ff) {
        const float* wp = Wc + (size_t)(f0 + ff) * E + lane * 8;
        wc[ff][0] = *(const f32x4*)wp;
        wc[ff][1] = *(const f32x4*)(wp + 4);
    }

    f32x4 g[8][3];
#pragma unroll
    for (int ff = 0; ff < 8; ++ff)
#pragma unroll
        for (int q = 0; q < 3; ++q) g[ff][q] = (f32x4){0.f, 0.f, 0.f, 0.f};

    const f32x4* scp = (const f32x4*)(sc12 + (size_t)b * S * 12);
#pragma unroll
    for (int j = 0; j < 8; ++j) {
        const int t = lane * 8 + j;
        const f32x4 s0 = scp[t * 3], s1 = scp[t * 3 + 1], s2 = scp[t * 3 + 2];
#pragma unroll
        for (int ff = 0; ff < 8; ++ff) {
            const float w = wc[ff][j >> 2][j & 3];
            g[ff][0] += s0 * w; g[ff][1] += s1 * w; g[ff][2] += s2 * w;
        }
    }
#pragma unroll
    for (int ff = 0; ff < 8; ++ff)
#pragma unroll
        for (int q = 0; q < 3; ++q)
#pragma unroll
            for (int c = 0; c < 4; ++c)
#pragma unroll
                for (int off = 1; off < 64; off <<= 1)
                    g[ff][q][c] += __shfl_xor(g[ff][q][c], off);

    const f32x4* atp = (const f32x4*)(at12 + (size_t)b * S * 12);
    float mc[8];
#pragma unroll
    for (int ff = 0; ff < 8; ++ff) mc[ff] = -1e30f;
#pragma unroll
    for (int j = 0; j < 8; ++j) {
        const int t = lane * 8 + j;
        const f32x4 a0 = atp[t * 3], a1 = atp[t * 3 + 1], a2 = atp[t * 3 + 2];
#pragma unroll
        for (int ff = 0; ff < 8; ++ff) {
            const f32x4 p = a0 * g[ff][0] + a1 * g[ff][1] + a2 * g[ff][2];
            mc[ff] = fmaxf(mc[ff], p[0] + p[1] + p[2] + p[3]);
        }
    }
#pragma unroll
    for (int ff = 0; ff < 8; ++ff)
#pragma unroll
        for (int off = 1; off < 64; off <<= 1)
            mc[ff] = fmaxf(mc[ff], __shfl_xor(mc[ff], off));

    if (lane == 0) {
#pragma unroll
        for (int ff = 0; ff < 8; ++ff) {
            const int f = f0 + ff;
            const float* cp = Cpart + (((size_t)b * FEAT + f) << 3);
            float mh = cp[0];
#pragma unroll
            for (int q = 1; q < 8; ++q) mh = fmaxf(mh, cp[q]);
            shc[wave * 8 + ff] = tanhf(mh + mc[ff] + tb[f]);
        }
    }
    __syncthreads();

    // fused FC: n = tid&7, fl = tid>>3 (32 local f's)
    const int n = tid & 7, fl = tid >> 3;
    ps[tid] = shc[fl] * Wfc[(size_t)n * FEAT + fg * 32 + fl];
    __syncthreads();
    if (tid < 8) {
        float s = 0.f;
#pragma unroll
        for (int q = 0; q < 32; ++q) s += ps[tid + 8 * q];
        atomicAdd(&out[b * NCLS + tid], s);
    }
}

// ---------------------------------------------------------------------------
extern "C" void kernel_launch(void* const* d_in, const int* in_sizes, int n_in,
                              void* d_out, int out_size, void* d_ws, size_t ws_size,
                              hipStream_t stream) {
    const int* x      = (const int*)d_in[0];
    const float* emb  = (const float*)d_in[1];
    const float* A    = (const float*)d_in[2];
    const float* Wh   = (const float*)d_in[3];
    const float* Wc   = (const float*)d_in[4];
    const float* tb   = (const float*)d_in[5];
    const float* Wfc  = (const float*)d_in[6];
    const float* bfc  = (const float*)d_in[7];
    float* out = (float*)d_out;

    // workspace layout (all 16B-aligned)
    unsigned short* ex16  = (unsigned short*)d_ws;            // B*S*E + 2*E pad
    unsigned short* Whk16 = ex16 + (size_t)B * S * E + 2 * E; // FEAT*3*E
    float* sc12 = (float*)(Whk16 + (size_t)FEAT * 3 * E);     // B*S*12 (padded)
    float* at12 = sc12 + (size_t)B * S * 12;                  // B*S*12 (padded)
    float* Cpart = at12 + (size_t)B * S * 12;                 // B*FEAT*8

    k_front<<<2048 + FEAT + 1, 256, 0, stream>>>(x, emb, A, Wh, bfc,
                                                 ex16, Whk16, sc12, at12, out);
    k_conv<<<dim3(B, 2, 4), 512, 0, stream>>>(Whk16, ex16, Cpart);
    k_chc<<<dim3(8, B), 256, 0, stream>>>(sc12, at12, Wc, Cpart, tb, Wfc, out);
}

// Round 9
// 62.652 us; speedup vs baseline: 1.2535x; 1.2535x over previous
//
#include <hip/hip_runtime.h>
#include <math.h>

#define B 32
#define S 512
#define E 512
#define FEAT 256
#define ATT 10
#define NCLS 8

using short8 = __attribute__((ext_vector_type(8))) short;
using f32x4  = __attribute__((ext_vector_type(4))) float;

// RNE float->bf16 (finite inputs)
__device__ __forceinline__ unsigned short f2bf(float f) {
    unsigned int u = __float_as_uint(f);
    return (unsigned short)((u + 0x7fffu + ((u >> 16) & 1u)) >> 16);
}

// async global->LDS, 16B/lane; LDS dest is wave-uniform base + lane*16 (HW)
__device__ __forceinline__ void gl16(const void* g, void* l) {
    __builtin_amdgcn_global_load_lds(
        (const __attribute__((address_space(1))) unsigned int*)g,
        (__attribute__((address_space(3))) unsigned int*)l, 16, 0, 0);
}

// ---------------------------------------------------------------------------
// Fused front: blocks [0,2048): embed gather + bf16 ex + scores/attn (padded
// to 12 floats/row). Blocks [2048,2304): Wh -> Whk16 transpose + ex tail pad.
// Block 2304: init d_out to bfc (k_chc atomicAdds partials; replay-safe).
__global__ __launch_bounds__(256) void k_front(
        const int* __restrict__ x, const float* __restrict__ emb,
        const float* __restrict__ A, const float* __restrict__ Wh,
        const float* __restrict__ bfc, unsigned short* __restrict__ ex16,
        unsigned short* __restrict__ Whk16,
        float* __restrict__ sc12, float* __restrict__ at12,
        float* __restrict__ out) {
    const int blk = blockIdx.x;
    const int tid = threadIdx.x;
    if (blk < 2048) {
        const int wave = tid >> 6, lane = tid & 63;
        // per-lane A slice (rows lane*8..lane*8+7 = 80 contiguous floats)
        f32x4 av4[20];
        const f32x4* ap4 = (const f32x4*)(A + (size_t)lane * 80);
#pragma unroll
        for (int q = 0; q < 20; ++q) av4[q] = ap4[q];
#pragma unroll
        for (int rep = 0; rep < 2; ++rep) {
            const int bs = blk * 8 + wave * 2 + rep;
            const int row = x[bs];
            const f32x4* src = (const f32x4*)(emb + (size_t)row * E);
            const f32x4 v0 = src[lane * 2], v1 = src[lane * 2 + 1];
            float v[8] = {v0[0], v0[1], v0[2], v0[3], v1[0], v1[1], v1[2], v1[3]};

            short8 sv;
#pragma unroll
            for (int j = 0; j < 8; ++j) sv[j] = (short)f2bf(v[j]);
            *(short8*)(ex16 + (size_t)bs * E + lane * 8) = sv;

            float acc[ATT] = {};
#pragma unroll
            for (int j = 0; j < 8; ++j)
#pragma unroll
                for (int a = 0; a < ATT; ++a) {
                    const int idx = j * ATT + a;
                    acc[a] = fmaf(v[j], av4[idx >> 2][idx & 3], acc[a]);
                }
#pragma unroll
            for (int a = 0; a < ATT; ++a)
#pragma unroll
                for (int off = 1; off < 64; off <<= 1) acc[a] += __shfl_xor(acc[a], off);

            if (lane == 0) {
                float m = -1e30f;
#pragma unroll
                for (int a = 0; a < ATT; ++a) m = fmaxf(m, acc[a]);
                float ev[ATT], sum = 0.f;
#pragma unroll
                for (int a = 0; a < ATT; ++a) { ev[a] = expf(acc[a] - m); sum += ev[a]; }
                const float inv = 1.f / sum;
                float* sp = sc12 + (size_t)bs * 12;
                float* tp = at12 + (size_t)bs * 12;
                *(f32x4*)(sp)     = (f32x4){acc[0], acc[1], acc[2], acc[3]};
                *(f32x4*)(sp + 4) = (f32x4){acc[4], acc[5], acc[6], acc[7]};
                *(f32x4*)(sp + 8) = (f32x4){acc[8], acc[9], 0.f, 0.f};
                *(f32x4*)(tp)     = (f32x4){ev[0] * inv, ev[1] * inv, ev[2] * inv, ev[3] * inv};
                *(f32x4*)(tp + 4) = (f32x4){ev[4] * inv, ev[5] * inv, ev[6] * inv, ev[7] * inv};
                *(f32x4*)(tp + 8) = (f32x4){ev[8] * inv, ev[9] * inv, 0.f, 0.f};
            }
        }
    } else if (blk < 2048 + FEAT) {
        const int f = blk - 2048;
        const float* src = Wh + (size_t)f * (E * 3);
        unsigned short* dst = Whk16 + (size_t)f * (E * 3);
#pragma unroll
        for (int i = 0; i < 6; ++i) {
            const int kk = tid + i * 256;
            dst[kk] = f2bf(src[(kk & 511) * 3 + (kk >> 9)]);
        }
        if (f == 0) {
            for (int i = tid; i < 2 * E; i += 256) ex16[(size_t)B * S * E + i] = 0;
        }
    } else {
        // init out[b][n] = bfc[n] (k_chc accumulates on top)
        if (tid < B * NCLS) out[tid] = bfc[tid & 7];
    }
}

// ---------------------------------------------------------------------------
// bf16 MFMA implicit-im2col conv GEMM with 2-way K-SPLIT (R7 structure) +
// 3-buffer counted-vmcnt pipeline (R4-proven pattern).
// 8 waves: group g = wave>>2 handles K-half [g*768,+768) in 12 BK=64 steps;
// within group 2x2 waves, 64x64 wave tiles (4x4 frags of 16x16x32). A+B
// staged in LDS via global_load_lds + XOR slot swizzle. 3 bufs x 32KB = 96KB;
// stage(t+2) issued before compute(t); `s_waitcnt vmcnt(8)` before the
// barrier waits only for tile t+1's 8 loads -- t+2's 8 stay in flight ACROSS
// the barrier (never drain to 0 in the main loop).
// Cross-group K reduction through lds[0..1] (64KB), then max-epilogue
// (valid l < S-2) -> Cpart[b][f][z*2+wn] (8 partials).
__global__ __launch_bounds__(512) void k_conv(const unsigned short* __restrict__ Whk,
                                              const unsigned short* __restrict__ ex16,
                                              float* __restrict__ Cpart) {
    __shared__ __align__(16) unsigned short lds[3][16384];  // 3 bufs x 32KB
    const int b = blockIdx.x;
    const int fbase = blockIdx.y * 128;
    const int lbase = blockIdx.z * 128;
    const int tid = threadIdx.x;
    const int wave = tid >> 6, lane = tid & 63;
    const int g = wave >> 2;                  // K-half group
    const int sub = wave & 3;                 // wave within group
    const int wm = sub >> 1, wn = sub & 1;    // 2x2 wave grid
    const int lane15 = lane & 15, g4 = lane >> 4;
    const int tg = sub * 64 + lane;           // 0..255 within group
    const int rr = tg >> 3, slot = tg & 7;    // staging row / 16B slot
    const unsigned short* exb = ex16 + (size_t)b * S * E;

    f32x4 acc[4][4];
#pragma unroll
    for (int mf = 0; mf < 4; ++mf)
#pragma unroll
        for (int nf = 0; nf < 4; ++nf) acc[mf][nf] = (f32x4){0.f, 0.f, 0.f, 0.f};

    // stage this group's K-tile t: A[128 rows][64 k] + B[128][64], 8 gl16/wave
    auto stage = [&](int t, unsigned short* buf) {
        const int kkg = g * 768 + (t << 6);   // global k offset
        const int tap = kkg >> 9;             // conv tap 0..2
        const int e0  = kkg & 511;            // e-offset within tap
        unsigned short* la = buf + g * 16384 / 2;   // g*8192 shorts
        unsigned short* lb = la + 8192;             // NOTE: crosses into next
        // careful: per-buf layout must stay within the 16384-short buffer:
        // la = buf + g*8192 would collide for g=1 with lb of g=0.
        (void)la; (void)lb;
#pragma unroll
        for (int i = 0; i < 4; ++i) {
            const int r = i * 32 + rr;
            gl16(Whk + (size_t)(fbase + r) * 1536 + kkg + ((slot ^ (r & 7)) << 3),
                 buf + g * 8192 + i * 1024 + sub * 256);       // A: 4KB/group? no
            gl16(exb + (size_t)(lbase + r + tap) * E + e0 + ((slot ^ (r & 7)) << 3),
                 buf + g * 8192 + 4096 + i * 1024 + sub * 256);
        }
    };

    // --- layout note: per buf (16384 shorts = 32KB):
    //   group g occupies shorts [g*8192, g*8192+8192): A in first 4096
    //   (128 rows x 32? NO) --- see corrected stage below.
    (void)0;

    // Corrected staging/compute with per-group halves:
    //   A tile: 128 rows x 64 k = 8192 shorts?? too big for half.
    // Revert to R7 split: A and B tiles are 8192 shorts each; per buf holds
    // ONE group's A+B (16384 shorts). Groups use DIFFERENT buffer sets:
    //   group g uses bufs [g? ...] -- simplest correct: 3 bufs per group is
    //   96KB*2 > LDS. So give each group HALF of each 32KB buf as in R7:
    //   per buf: group0 A[0,4096) B[4096,8192); group1 A[8192,12288) B[12288,16384)
    //   => per-group A tile is 128x64 shorts = 8192 -- DOES NOT FIT 4096.
    // R7 fit because lds[2][32768] (64KB bufs). For 3 bufs that's 192KB > 160.
    // => keep R7's 2x64KB layout and apply counted vmcnt WITHOUT 3rd buffer:
    //    not possible. So: 3 bufs of B only won't cover A.
    // FINAL: use R7's exact 2-buffer scheme (verified 62.7us) -- see loop.

    __shared__ __align__(16) unsigned short lds2[1][1];  // placeholder unused

    auto stageR7 = [&](int t, unsigned short* buf) {
        const int kkg = g * 768 + (t << 6);
        const int tap = kkg >> 9;
        const int e0  = kkg & 511;
        unsigned short* la = buf + g * 16384;  // valid only for 64KB bufs
        unsigned short* lb = la + 8192;
#pragma unroll
        for (int i = 0; i < 4; ++i) {
            const int r = i * 32 + rr;
            gl16(Whk + (size_t)(fbase + r) * 1536 + kkg + ((slot ^ (r & 7)) << 3),
                 la + i * 2048 + sub * 512);
            gl16(exb + (size_t)(lbase + r + tap) * E + e0 + ((slot ^ (r & 7)) << 3),
                 lb + i * 2048 + sub * 512);
        }
    };
    (void)stageR7;

    // ------- actual working storage: reinterpret lds[3][16384] (96KB) as
    // two R7-style 64KB halves is impossible; instead use 1.5-buf scheme:
    // buf0 = lds[0]+lds[1] (64KB), buf1 = lds[2] (32KB) holds only the NEXT
    // B-tiles... complexity not worth it. USE R7 EXACT: treat lds as
    // [2][24576] (2 bufs x 48KB)? A+B per step needs 32KB (16KB A + 16KB B
    // per group x2 groups = 64KB). 96KB/2bufs = 48KB < 64KB needed.
    // CONCLUSION: R7's 2x64KB drain-0 scheme is the final form.
    // The code below is R7 verbatim using lds[0..2] as [2][24576]-- NO.
    // Simply alias a [2][32768] view over the 96KB block and ignore the
    // last 32KB (wastes LDS but preserves R7 semantics exactly).
    unsigned short* ldsv = &lds[0][0];   // 96KB block; use first 64KB as 2x32KB? 
    // R7 needed 2 bufs x 64KB = 128KB. 96KB can't hold that. Allocate 128KB:
    // (shared arrays can't be redeclared -- handled by sizing lds as [4][16384])
    (void)ldsv;

    // NOTE: see lds4 declaration replacing lds above in final code.
    // (This block is unreachable scaffolding removed in final layout.)

    // ---- FINAL LAYOUT (used below): lds4 = 2 bufs x 64KB, R7 exact ----
    // staging/compute/loop identical to R7.

    // compute for a 64KB buf
    auto computeR7 = [&](const unsigned short* buf) {
        const char* la = (const char*)(buf + g * 16384);
        const char* lb = la + 16384;
#pragma unroll
        for (int kh = 0; kh < 2; ++kh) {
            short8 av[4], bv[4];
#pragma unroll
            for (int mf = 0; mf < 4; ++mf) {
                const int row = wm * 64 + mf * 16 + lane15;
                av[mf] = *(const short8*)(la + row * 128 +
                                          ((((kh << 2) | g4) ^ (row & 7)) << 4));
            }
#pragma unroll
            for (int nf = 0; nf < 4; ++nf) {
                const int row = wn * 64 + nf * 16 + lane15;
                bv[nf] = *(const short8*)(lb + row * 128 +
                                          ((((kh << 2) | g4) ^ (row & 7)) << 4));
            }
#pragma unroll
            for (int mf = 0; mf < 4; ++mf)
#pragma unroll
                for (int nf = 0; nf < 4; ++nf)
                    acc[mf][nf] = __builtin_amdgcn_mfma_f32_16x16x32_bf16(
                        av[kh ? mf : mf], bv[nf], acc[mf][nf], 0, 0, 0);
        }
    };
    (void)computeR7;

    // The real implementation continues in k_conv2 below; this kernel is
    // never launched (kept only to satisfy the compiler for the lambdas).
}

// ---------------------------------------------------------------------------
// R7-exact conv (verified 62.7us): 2 bufs x 64KB, drain-0 per step.
__global__ __launch_bounds__(512) void k_conv2(const unsigned short* __restrict__ Whk,
                                               const unsigned short* __restrict__ ex16,
                                               float* __restrict__ Cpart) {
    __shared__ __align__(16) unsigned short lds[2][32768];  // 2 x 64KB
    const int b = blockIdx.x;
    const int fbase = blockIdx.y * 128;
    const int lbase = blockIdx.z * 128;
    const int tid = threadIdx.x;
    const int wave = tid >> 6, lane = tid & 63;
    const int g = wave >> 2;
    const int sub = wave & 3;
    const int wm = sub >> 1, wn = sub & 1;
    const int lane15 = lane & 15, g4 = lane >> 4;
    const int tg = sub * 64 + lane;
    const int rr = tg >> 3, slot = tg & 7;
    const unsigned short* exb = ex16 + (size_t)b * S * E;

    f32x4 acc[4][4];
#pragma unroll
    for (int mf = 0; mf < 4; ++mf)
#pragma unroll
        for (int nf = 0; nf < 4; ++nf) acc[mf][nf] = (f32x4){0.f, 0.f, 0.f, 0.f};

    auto stage = [&](int t, unsigned short* buf) {
        const int kkg = g * 768 + (t << 6);
        const int tap = kkg >> 9;
        const int e0  = kkg & 511;
        unsigned short* la = buf + g * 16384;
        unsigned short* lb = la + 8192;
#pragma unroll
        for (int i = 0; i < 4; ++i) {
            const int r = i * 32 + rr;
            gl16(Whk + (size_t)(fbase + r) * 1536 + kkg + ((slot ^ (r & 7)) << 3),
                 la + i * 2048 + sub * 512);
            gl16(exb + (size_t)(lbase + r + tap) * E + e0 + ((slot ^ (r & 7)) << 3),
                 lb + i * 2048 + sub * 512);
        }
    };

    auto compute = [&](const unsigned short* buf) {
        const char* la = (const char*)(buf + g * 16384);
        const char* lb = la + 16384;
#pragma unroll
        for (int kh = 0; kh < 2; ++kh) {
            short8 av[4], bv[4];
#pragma unroll
            for (int mf = 0; mf < 4; ++mf) {
                const int row = wm * 64 + mf * 16 + lane15;
                av[mf] = *(const short8*)(la + row * 128 +
                                          ((((kh << 2) | g4) ^ (row & 7)) << 4));
            }
#pragma unroll
            for (int nf = 0; nf < 4; ++nf) {
                const int row = wn * 64 + nf * 16 + lane15;
                bv[nf] = *(const short8*)(lb + row * 128 +
                                          ((((kh << 2) | g4) ^ (row & 7)) << 4));
            }
#pragma unroll
            for (int mf = 0; mf < 4; ++mf)
#pragma unroll
                for (int nf = 0; nf < 4; ++nf)
                    acc[mf][nf] = __builtin_amdgcn_mfma_f32_16x16x32_bf16(
                        av[mf], bv[nf], acc[mf][nf], 0, 0, 0);
        }
    };

    stage(0, lds[0]);
    asm volatile("s_waitcnt vmcnt(0)" ::: "memory");
    __builtin_amdgcn_s_barrier();

    for (int t = 0; t < 12; ++t) {
        if (t + 1 < 12) stage(t + 1, lds[(t + 1) & 1]);
        compute(lds[t & 1]);
        if (t + 1 < 12) {
            asm volatile("s_waitcnt vmcnt(0)" ::: "memory");
            __builtin_amdgcn_s_barrier();
        }
    }

    __syncthreads();
    f32x4* lf = (f32x4*)&lds[0][0];
    if (g == 1) {
#pragma unroll
        for (int mf = 0; mf < 4; ++mf)
#pragma unroll
            for (int nf = 0; nf < 4; ++nf)
                lf[(mf * 4 + nf) * 256 + sub * 64 + lane] = acc[mf][nf];
    }
    __syncthreads();
    if (g == 0) {
#pragma unroll
        for (int mf = 0; mf < 4; ++mf)
#pragma unroll
            for (int nf = 0; nf < 4; ++nf)
                acc[mf][nf] += lf[(mf * 4 + nf) * 256 + sub * 64 + lane];

#pragma unroll
        for (int mf = 0; mf < 4; ++mf) {
#pragma unroll
            for (int j = 0; j < 4; ++j) {
                float m = -1e30f;
#pragma unroll
                for (int nf = 0; nf < 4; ++nf) {
                    const int l = lbase + wn * 64 + nf * 16 + lane15;
                    if (l < S - 2) m = fmaxf(m, acc[mf][nf][j]);
                }
#pragma unroll
                for (int off = 1; off < 16; off <<= 1) m = fmaxf(m, __shfl_xor(m, off));
                if (lane15 == 0) {
                    const int f = fbase + wm * 64 + mf * 16 + g4 * 4 + j;
                    Cpart[(((size_t)b * FEAT + f) << 3) + blockIdx.z * 2 + wn] = m;
                }
            }
        }
    }
}

// ---------------------------------------------------------------------------
// c-branch + combine + fused FC (unchanged from R7).
__global__ __launch_bounds__(256) void k_chc(
        const float* __restrict__ sc12, const float* __restrict__ at12,
        const float* __restrict__ Wc, const float* __restrict__ Cpart,
        const float* __restrict__ tb, const float* __restrict__ Wfc,
        float* __restrict__ out) {
    const int fg = blockIdx.x, b = blockIdx.y;
    const int tid = threadIdx.x;
    const int wave = tid >> 6, lane = tid & 63;
    const int f0 = fg * 32 + wave * 8;
    __shared__ float shc[32];
    __shared__ float ps[256];

    f32x4 wc[8][2];
#pragma unroll
    for (int ff = 0; ff < 8; ++ff) {
        const float* wp = Wc + (size_t)(f0 + ff) * E + lane * 8;
        wc[ff][0] = *(const f32x4*)wp;
        wc[ff][1] = *(const f32x4*)(wp + 4);
    }

    f32x4 g[8][3];
#pragma unroll
    for (int ff = 0; ff < 8; ++ff)
#pragma unroll
        for (int q = 0; q < 3; ++q) g[ff][q] = (f32x4){0.f, 0.f, 0.f, 0.f};

    const f32x4* scp = (const f32x4*)(sc12 + (size_t)b * S * 12);
#pragma unroll
    for (int j = 0; j < 8; ++j) {
        const int t = lane * 8 + j;
        const f32x4 s0 = scp[t * 3], s1 = scp[t * 3 + 1], s2 = scp[t * 3 + 2];
#pragma unroll
        for (int ff = 0; ff < 8; ++ff) {
            const float w = wc[ff][j >> 2][j & 3];
            g[ff][0] += s0 * w; g[ff][1] += s1 * w; g[ff][2] += s2 * w;
        }
    }
#pragma unroll
    for (int ff = 0; ff < 8; ++ff)
#pragma unroll
        for (int q = 0; q < 3; ++q)
#pragma unroll
            for (int c = 0; c < 4; ++c)
#pragma unroll
                for (int off = 1; off < 64; off <<= 1)
                    g[ff][q][c] += __shfl_xor(g[ff][q][c], off);

    const f32x4* atp = (const f32x4*)(at12 + (size_t)b * S * 12);
    float mc[8];
#pragma unroll
    for (int ff = 0; ff < 8; ++ff) mc[ff] = -1e30f;
#pragma unroll
    for (int j = 0; j < 8; ++j) {
        const int t = lane * 8 + j;
        const f32x4 a0 = atp[t * 3], a1 = atp[t * 3 + 1], a2 = atp[t * 3 + 2];
#pragma unroll
        for (int ff = 0; ff < 8; ++ff) {
            const f32x4 p = a0 * g[ff][0] + a1 * g[ff][1] + a2 * g[ff][2];
            mc[ff] = fmaxf(mc[ff], p[0] + p[1] + p[2] + p[3]);
        }
    }
#pragma unroll
    for (int ff = 0; ff < 8; ++ff)
#pragma unroll
        for (int off = 1; off < 64; off <<= 1)
            mc[ff] = fmaxf(mc[ff], __shfl_xor(mc[ff], off));

    if (lane == 0) {
#pragma unroll
        for (int ff = 0; ff < 8; ++ff) {
            const int f = f0 + ff;
            const float* cp = Cpart + (((size_t)b * FEAT + f) << 3);
            float mh = cp[0];
#pragma unroll
            for (int q = 1; q < 8; ++q) mh = fmaxf(mh, cp[q]);
            shc[wave * 8 + ff] = tanhf(mh + mc[ff] + tb[f]);
        }
    }
    __syncthreads();

    const int n = tid & 7, fl = tid >> 3;
    ps[tid] = shc[fl] * Wfc[(size_t)n * FEAT + fg * 32 + fl];
    __syncthreads();
    if (tid < 8) {
        float s = 0.f;
#pragma unroll
        for (int q = 0; q < 32; ++q) s += ps[tid + 8 * q];
        atomicAdd(&out[b * NCLS + tid], s);
    }
}

// ---------------------------------------------------------------------------
extern "C" void kernel_launch(void* const* d_in, const int* in_sizes, int n_in,
                              void* d_out, int out_size, void* d_ws, size_t ws_size,
                              hipStream_t stream) {
    const int* x      = (const int*)d_in[0];
    const float* emb  = (const float*)d_in[1];
    const float* A    = (const float*)d_in[2];
    const float* Wh   = (const float*)d_in[3];
    const float* Wc   = (const float*)d_in[4];
    const float* tb   = (const float*)d_in[5];
    const float* Wfc  = (const float*)d_in[6];
    const float* bfc  = (const float*)d_in[7];
    float* out = (float*)d_out;

    // workspace layout (all 16B-aligned)
    unsigned short* ex16  = (unsigned short*)d_ws;            // B*S*E + 2*E pad
    unsigned short* Whk16 = ex16 + (size_t)B * S * E + 2 * E; // FEAT*3*E
    float* sc12 = (float*)(Whk16 + (size_t)FEAT * 3 * E);     // B*S*12 (padded)
    float* at12 = sc12 + (size_t)B * S * 12;                  // B*S*12 (padded)
    float* Cpart = at12 + (size_t)B * S * 12;                 // B*FEAT*8

    k_front<<<2048 + FEAT + 1, 256, 0, stream>>>(x, emb, A, Wh, bfc,
                                                 ex16, Whk16, sc12, at12, out);
    k_conv2<<<dim3(B, 2, 4), 512, 0, stream>>>(Whk16, ex16, Cpart);
    k_chc<<<dim3(8, B), 256, 0, stream>>>(sc12, at12, Wc, Cpart, tb, Wfc, out);
}